// Round 7
// baseline (23.799 us; speedup 1.0000x reference)
//
#include <hip/hip_runtime.h>

// x: [2,2,8,64,64,64] fp32 0/1 -> 2048 images of 64x64.
// Per image: #4-connected components; per group of 64 images: sum // 64 -> float.
//
// One 256-thread block per image; thread = 4*row + quarter. Threads build row
// masks in registers (16 px/thread, width-4 shuffle butterfly). Horizontal
// runs are free (bitmask). Vertical overlap segments are PACKED into a
// per-wave LDS worklist (shuffle prefix-sum for offsets) so the union loop
// runs fully-occupied instead of at wave-max divergence. Unions use Rem's
// algorithm with atomicMin splicing (one read + one atomicMin per step,
// in-walk compression, no CAS retry convoys).
// components = total_runs - root_kills; plain store + tiny reduce kernel.
constexpr int NPIX = 64 * 64;
constexpr int PATCHES = 64;
constexpr int RUNS_PER_ROW = 32;
constexpr int TABLE = 64 * RUNS_PER_ROW;  // 2048 run slots
constexpr int WL_PER_WAVE = 512;          // exact bound: 8 seg/lane * 64

// Rem's algorithm with atomicMin splicing.
//  - parents only ever decrease (atomicMin with in-component smaller values)
//    -> walks strictly descend, terminate; non-roots never become roots.
//  - exactly one p[root] transitions away from self per component merge; the
//    thread whose atomicMin returns the old root value counts it.
//  - splice (x non-root): py < px < x, links x toward the other chain while
//    ascending; races only lower parents within the merged component.
__device__ __forceinline__ int merge(int* p, int x, int y) {
    int px = p[x], py = p[y];
    while (px != py) {
        if (px < py) { int t = x; x = y; y = t; t = px; px = py; py = t; }
        if (px == x) {                       // x is root
            int old = atomicMin(&p[x], py);
            if (old == x) return 1;          // we killed root x
            px = old;                        // root moved; continue walk
        } else {                             // splice and ascend
            atomicMin(&p[x], py);
            x = px;
            px = p[x];
        }
    }
    return 0;  // chains met -> already connected
}

__global__ __launch_bounds__(256, 8) void cc_kernel(const float* __restrict__ in,
                                                    int* __restrict__ counts) {
    __shared__ int par[TABLE];               // 8 KB
    __shared__ unsigned long long mrow[64];  // 512 B
    __shared__ unsigned wl[4][WL_PER_WAVE];  // 8 KB worklists
    __shared__ int wpart[4];
    const int tid = threadIdx.x;
    const int img = blockIdx.x;
    const int r = tid >> 2;   // row 0..63
    const int q = tid & 3;    // quarter 0..3
    const int wid = tid >> 6; // wave 0..3
    const int lane = tid & 63;

    // ---- load 16 consecutive pixels (4 x float4 = one 64B line) ----
    const float4* src =
        reinterpret_cast<const float4*>(in + (size_t)img * NPIX + r * 64 + q * 16);
    float4 buf[4];
#pragma unroll
    for (int k = 0; k < 4; ++k) buf[k] = src[k];

    // ---- identity-init run table while loads are in flight ----
    {
        int b0 = tid * 4;
        *reinterpret_cast<int4*>(&par[b0]) = make_int4(b0, b0 + 1, b0 + 2, b0 + 3);
        int b1 = 1024 + tid * 4;
        *reinterpret_cast<int4*>(&par[b1]) = make_int4(b1, b1 + 1, b1 + 2, b1 + 3);
    }

    // ---- 16-bit quarter mask, then full row mask via width-4 butterfly ----
    unsigned qm = 0;
#pragma unroll
    for (int k = 0; k < 4; ++k) {
        qm |= (buf[k].x > 0.5f ? 1u : 0u) << (4 * k);
        qm |= (buf[k].y > 0.5f ? 2u : 0u) << (4 * k);
        qm |= (buf[k].z > 0.5f ? 4u : 0u) << (4 * k);
        qm |= (buf[k].w > 0.5f ? 8u : 0u) << (4 * k);
    }
    unsigned long long m = (unsigned long long)qm << (16 * q);
    m |= __shfl_xor(m, 1, 4);
    m |= __shfl_xor(m, 2, 4);  // all 4 threads of row r hold the full mask

    if (q == 0) mrow[r] = m;
    __syncthreads();  // par + mrow visible

    const unsigned long long ma = m;
    const unsigned long long mb = (r < 63) ? mrow[r + 1] : 0ull;
    const unsigned long long sa = ma & ~(ma << 1);
    const unsigned long long sb = mb & ~(mb << 1);
    const unsigned long long qmask = 0xFFFFull << (16 * q);

    int cnt = __popcll(sa & qmask);  // run starts partitioned by quarter

    // ---- enumerate overlap segments starting in this quarter ----
    unsigned long long both = ma & mb;
    unsigned long long ov = (both & ~(both << 1)) & qmask;
    const int nseg = __popcll(ov);

    // wave-wide exclusive prefix sum of segment counts
    int pre = nseg;
#pragma unroll
    for (int d = 1; d < 64; d <<= 1) {
        int t = __shfl_up(pre, d, 64);
        if (lane >= d) pre += t;
    }
    const int wtotal = __shfl(pre, 63, 64);  // wave's total segments
    int idx = pre - nseg;                    // exclusive base

    while (ov) {
        int x = __builtin_ctzll(ov);
        ov &= ov - 1;
        unsigned long long below = (2ull << x) - 1;  // bits 0..x
        int ida = r * RUNS_PER_ROW + __popcll(sa & below) - 1;
        int idb = (r + 1) * RUNS_PER_ROW + __popcll(sb & below) - 1;
        wl[wid][idx++] = ((unsigned)ida << 11) | (unsigned)idb;
    }
    __syncthreads();  // worklists visible

    // ---- balanced union loop: lanes consume the wave's list round-robin ----
    for (int t = lane; t < wtotal; t += 64) {
        unsigned pr = wl[wid][t];
        cnt -= merge(par, (int)(pr >> 11), (int)(pr & 2047u));
    }

    // ---- block reduction of (runs - kills); plain store ----
#pragma unroll
    for (int d = 32; d > 0; d >>= 1) cnt += __shfl_xor(cnt, d, 64);
    if (lane == 0) wpart[wid] = cnt;
    __syncthreads();
    if (tid == 0) counts[img] = wpart[0] + wpart[1] + wpart[2] + wpart[3];
}

// One block: group g = 8 threads summing its 64 per-image counts.
__global__ void finalize_kernel(const int* __restrict__ counts,
                                float* __restrict__ out, int ngroups) {
    const int t = threadIdx.x;
    const int g = t >> 3, j = t & 7;
    if (g >= ngroups) return;
    const int* c = counts + g * PATCHES + j * 8;
    int s = 0;
#pragma unroll
    for (int k = 0; k < 8; ++k) s += c[k];
#pragma unroll
    for (int d = 4; d > 0; d >>= 1) s += __shfl_down(s, d, 8);
    if (j == 0) out[g] = (float)(s >> 6);  // sum // 64 (sum >= 0)
}

extern "C" void kernel_launch(void* const* d_in, const int* in_sizes, int n_in,
                              void* d_out, int out_size, void* d_ws, size_t ws_size,
                              hipStream_t stream) {
    const float* x = (const float*)d_in[0];
    float* out = (float*)d_out;
    int* counts = (int*)d_ws;

    const int nimg = in_sizes[0] / NPIX;  // 2048
    const int ngroups = out_size;         // 32

    cc_kernel<<<nimg, 256, 0, stream>>>(x, counts);
    finalize_kernel<<<1, ngroups * 8, 0, stream>>>(counts, out, ngroups);
}